// Round 2
// baseline (167.174 us; speedup 1.0000x reference)
//
#include <hip/hip_runtime.h>

// y = q_tok(x) @ q_grp(W)^T + bias, factored exactly:
//   q(x) = g_x * s_x[m], q(W) = g_w * s_w[n,grp] (grp=128 along K)
//   y[m,n] = s_x[m] * sum_grp s_w[n,grp] * (sum_{k in grp} g_x g_w)
// R7: gemm restructured for overlap -- triple-buffered LDS, ONE barrier
// per K-group (stage AFTER barrier; slot (g+2)%3 was last read at g-1),
// prefetch depth 2 with counted vmcnt(4), two-phase MFMA with counted
// lgkmcnt so MFMAs start while trailing ds_reads are in flight.
// Quant x-role reverted to fully-coalesced float4 loads (R6 regression),
// packing 4 nibbles -> ushort stores (same xq layout as R6).

#define M_TOK 2048
#define N_OUT 4096
#define K_IN  4096
#define KB    2048    // packed fp4 bytes per K row (K_IN/2)
#define XBLK  2048    // x-role: one block per token row
#define WBLK  8192    // w-role: 2048 floats (16 groups) per block

typedef __attribute__((ext_vector_type(4))) int   int4v;
typedef __attribute__((ext_vector_type(8))) int   int8v;
typedef __attribute__((ext_vector_type(4))) float floatx4;

// fp4-e2m1 nibble via scale-premultiplied decision thresholds
// T = {.25,.75,1.25,1.75,2.5,3.5,5}*scale; codes 0..7 = {0,.5,1,1.5,2,3,4,6}
__device__ __forceinline__ unsigned int q_nib(
    float v, float t0, float t1, float t2, float t3, float t4, float t5, float t6)
{
    float a = fabsf(v);
    unsigned int m =
        a < t0 ? 0u : a < t1 ? 1u : a < t2 ? 2u : a < t3 ? 3u :
        a < t4 ? 4u : a < t5 ? 5u : a < t6 ? 6u : 7u;
    return m | ((__float_as_uint(v) >> 28) & 0x8u);
}

#define MK_THR(scale) \
    const float t0 = 0.25f * (scale), t1 = 0.75f * (scale), \
                t2 = 1.25f * (scale), t3 = 1.75f * (scale), \
                t4 = 2.5f  * (scale), t5 = 3.5f  * (scale), \
                t6 = 5.0f  * (scale);

// ---------- fused quant: blocks [0,XBLK) per-token x, rest per-group w ----------
__global__ __launch_bounds__(256) void quant_fused_kernel(
    const float* __restrict__ x, const float* __restrict__ w,
    unsigned char* __restrict__ xq, float* __restrict__ sx,
    unsigned char* __restrict__ wq, float* __restrict__ swt)
{
    const int t = threadIdx.x;
    const int lane = t & 63, wid = t >> 6;

    if (blockIdx.x < XBLK) {
        // ---- per-token row of 4096: clamp [-3,3], scale = absmax/6 ----
        // coalesced: phase i loads float4 at i*1024 + t*4 (16B/lane contiguous)
        const int row = blockIdx.x;
        const float* xr = x + (size_t)row * K_IN;
        float4 v[4];
        float amax = 0.0f;
        #pragma unroll
        for (int i = 0; i < 4; i++) {
            float4 a = *(const float4*)(xr + i * 1024 + t * 4);
            a.x = fminf(fmaxf(a.x, -3.0f), 3.0f);
            a.y = fminf(fmaxf(a.y, -3.0f), 3.0f);
            a.z = fminf(fmaxf(a.z, -3.0f), 3.0f);
            a.w = fminf(fmaxf(a.w, -3.0f), 3.0f);
            v[i] = a;
            amax = fmaxf(amax, fmaxf(fmaxf(fabsf(a.x), fabsf(a.y)),
                                     fmaxf(fabsf(a.z), fabsf(a.w))));
        }
        #pragma unroll
        for (int off = 32; off; off >>= 1)
            amax = fmaxf(amax, __shfl_xor(amax, off));
        __shared__ float smax[4];
        if (lane == 0) smax[wid] = amax;
        __syncthreads();
        amax = fmaxf(fmaxf(smax[0], smax[1]), fmaxf(smax[2], smax[3]));

        const float scale = amax / 6.0f;
        if (t == 0) sx[row] = scale;
        MK_THR(scale);
        unsigned char* xo = xq + (size_t)row * KB;
        #pragma unroll
        for (int i = 0; i < 4; i++) {
            unsigned int u = q_nib(v[i].x, t0,t1,t2,t3,t4,t5,t6)
                           | (q_nib(v[i].y, t0,t1,t2,t3,t4,t5,t6) << 4)
                           | (q_nib(v[i].z, t0,t1,t2,t3,t4,t5,t6) << 8)
                           | (q_nib(v[i].w, t0,t1,t2,t3,t4,t5,t6) << 12);
            *(unsigned short*)(xo + i * 512 + t * 2) = (unsigned short)u;
        }
    } else {
        // ---- per-group w: block = 2048 floats = 16 groups; 16 lanes/group,
        //      8 consecutive elements per lane -> one packed uint ----
        const int b = blockIdx.x - XBLK;
        const float* base = w + (size_t)b * 2048 + t * 8;
        float4 v0 = *(const float4*)base;
        float4 v1 = *(const float4*)(base + 4);
        float vals[8] = {v0.x, v0.y, v0.z, v0.w, v1.x, v1.y, v1.z, v1.w};
        float amax = 0.0f;
        #pragma unroll
        for (int j = 0; j < 8; j++) amax = fmaxf(amax, fabsf(vals[j]));
        #pragma unroll
        for (int off = 8; off; off >>= 1)   // reduce within 16-lane cluster
            amax = fmaxf(amax, __shfl_xor(amax, off));
        const float scale = amax / 6.0f;
        const int G = b * 16 + (t >> 4);    // flat group id = n*32 + gk
        if ((lane & 15) == 0) swt[(size_t)(G & 31) * N_OUT + (G >> 5)] = scale;
        MK_THR(scale);
        unsigned int u = 0;
        #pragma unroll
        for (int j = 0; j < 8; j++)
            u |= q_nib(vals[j], t0,t1,t2,t3,t4,t5,t6) << (4 * j);
        *(unsigned int*)(wq + (size_t)b * 1024 + t * 4) = u;
    }
}

// ---------- async 16B global->LDS ----------
__device__ __forceinline__ void gld16(const unsigned char* g, unsigned char* l) {
    __builtin_amdgcn_global_load_lds(
        (const __attribute__((address_space(1))) void*)g,
        (__attribute__((address_space(3))) void*)l, 16, 0, 0);
}

// ---------- MX-fp4 GEMM, BK=128 = one quant group per MFMA ----------
// Triple-buffered LDS, single barrier per K-group, prefetch depth 2,
// counted vmcnt/lgkmcnt, setprio(1) around the MFMA clusters.
__global__ __launch_bounds__(256) void gemm_mx4_kernel(
    const unsigned char* __restrict__ A, const float* __restrict__ sx,
    const unsigned char* __restrict__ B, const float* __restrict__ swt,
    const float* __restrict__ bias, float* __restrict__ C)
{
    __shared__ __align__(16) unsigned char As[3][128 * 64];  // 3 x 8 KB
    __shared__ __align__(16) unsigned char Bs[3][128 * 64];  // 3 x 8 KB
    __shared__ __align__(16) float svs[32][128];             // 16 KB scales

    const int tid = threadIdx.x;
    const int m0 = blockIdx.y * 128;
    const int n0 = blockIdx.x * 128;
    const int lane = tid & 63;
    const int wid  = tid >> 6;
    const int wm = (wid & 1) * 64;
    const int wn = (wid >> 1) * 64;
    const int lr = lane & 15;
    const int lq = lane >> 4;

    floatx4 mast[4][4] = {};

    // staging: 512 sub-chunks(16B) per buffer, 2/thread each for A and B;
    // rotation swizzle phys=(c+row)&3 (inverse applied on the global source
    // so the LDS dest stays wave-uniform + lane*16)
    const unsigned char* gA[2];
    const unsigned char* gB[2];
    int ldst[2];
    #pragma unroll
    for (int i = 0; i < 2; i++) {
        const int P = tid + i * 256;
        const int row = P >> 2, ph = P & 3;
        const int c = (ph - row) & 3;
        gA[i] = A + (size_t)(m0 + row) * KB + c * 16;
        gB[i] = B + (size_t)(n0 + row) * KB + c * 16;
        ldst[i] = P * 16;
    }

#define STAGE(gg, ss) do {                                     \
        const int koff_ = (gg) * 64;                           \
        _Pragma("unroll")                                      \
        for (int i_ = 0; i_ < 2; i_++) {                       \
            gld16(gA[i_] + koff_, &As[ss][ldst[i_]]);          \
            gld16(gB[i_] + koff_, &Bs[ss][ldst[i_]]);          \
        }                                                      \
    } while (0)

    // prologue: stage groups 0,1 into slots 0,1 (8 gld16 in flight)
    STAGE(0, 0);
    STAGE(1, 1);

    // one-time stage of this block's weight scales: swt[g][n0..n0+128)
    #pragma unroll
    for (int i = 0; i < 4; i++) {
        const int flat = tid + i * 256;          // float4 index, 1024 total
        const int g = flat >> 5, c = (flat & 31) << 2;
        *(float4*)&svs[g][c] = *(const float4*)(swt + (size_t)g * N_OUT + n0 + c);
    }
    asm volatile("s_waitcnt lgkmcnt(0)" ::: "memory");  // svs ds_writes done
    // (no barrier here: the loop's first barrier publishes svs + slot0)

    const floatx4 zero = {0.0f, 0.0f, 0.0f, 0.0f};
    int cur = 0;

    #pragma unroll 1
    for (int g = 0; g < 32; g++) {
        // wait for group g's 4 loads (g+1's 4 may stay in flight)
        if (g < 31) asm volatile("s_waitcnt vmcnt(4)" ::: "memory");
        else        asm volatile("s_waitcnt vmcnt(0)" ::: "memory");
        __builtin_amdgcn_s_barrier();      // slot[cur] published; slot[(cur+2)%3] free
        __builtin_amdgcn_sched_barrier(0);

        // stage group g+2 into the slot last read at iter g-1
        if (g < 30) {
            int s2 = cur + 2; if (s2 >= 3) s2 -= 3;
            STAGE(g + 2, s2);
        }

        // issue all ds_reads: sv(4 x b32), bf0..3, af0, af1 | af2, af3
        float sv[4];
        #pragma unroll
        for (int ni = 0; ni < 4; ni++)
            sv[ni] = svs[g][wn + ni * 16 + lr];

        int8v af[4], bf[4];
        #pragma unroll
        for (int ni = 0; ni < 4; ni++) {
            const int row = wn + ni * 16 + lr;
            const int slot = (lq + row) & 3;
            int4v d = *(const int4v*)&Bs[cur][row * 64 + slot * 16];
            bf[ni] = (int8v){d[0], d[1], d[2], d[3], 0, 0, 0, 0};
        }
        #pragma unroll
        for (int mi = 0; mi < 2; mi++) {
            const int row = wm + mi * 16 + lr;
            const int slot = (lq + row) & 3;
            int4v d = *(const int4v*)&As[cur][row * 64 + slot * 16];
            af[mi] = (int8v){d[0], d[1], d[2], d[3], 0, 0, 0, 0};
        }
        __builtin_amdgcn_sched_barrier(0);   // pin: af2/af3 issue after the above
        #pragma unroll
        for (int mi = 2; mi < 4; mi++) {
            const int row = wm + mi * 16 + lr;
            const int slot = (lq + row) & 3;
            int4v d = *(const int4v*)&As[cur][row * 64 + slot * 16];
            af[mi] = (int8v){d[0], d[1], d[2], d[3], 0, 0, 0, 0};
        }

        // phase A: sv+bf+af0/af1 ready (2 younger ds ops outstanding)
        asm volatile("s_waitcnt lgkmcnt(2)" ::: "memory");
        __builtin_amdgcn_sched_barrier(0);   // rule #18
        __builtin_amdgcn_s_setprio(1);
        #pragma unroll
        for (int mi = 0; mi < 2; mi++)
            #pragma unroll
            for (int ni = 0; ni < 4; ni++) {
                floatx4 tacc = __builtin_amdgcn_mfma_scale_f32_16x16x128_f8f6f4(
                    af[mi], bf[ni], zero, 4, 4,          // cbsz=blgp=4 -> fp4
                    0, 0x7F7F7F7F, 0, 0x7F7F7F7F);       // e8m0 scales = 1.0
                mast[mi][ni] += sv[ni] * tacc;
            }
        __builtin_amdgcn_s_setprio(0);

        // phase B: af2/af3 ready
        asm volatile("s_waitcnt lgkmcnt(0)" ::: "memory");
        __builtin_amdgcn_sched_barrier(0);   // rule #18
        __builtin_amdgcn_s_setprio(1);
        #pragma unroll
        for (int mi = 2; mi < 4; mi++)
            #pragma unroll
            for (int ni = 0; ni < 4; ni++) {
                floatx4 tacc = __builtin_amdgcn_mfma_scale_f32_16x16x128_f8f6f4(
                    af[mi], bf[ni], zero, 4, 4,
                    0, 0x7F7F7F7F, 0, 0x7F7F7F7F);
                mast[mi][ni] += sv[ni] * tacc;
            }
        __builtin_amdgcn_s_setprio(0);

        cur += 1; if (cur == 3) cur = 0;
    }

    // epilogue: C/D layout col=lane&15, row=(lane>>4)*4+reg [m89/m91]
    #pragma unroll
    for (int mi = 0; mi < 4; mi++) {
        const int rbase = m0 + wm + mi * 16 + lq * 4;
        #pragma unroll
        for (int ni = 0; ni < 4; ni++) {
            const int cc = n0 + wn + ni * 16 + lr;
            const float bb = bias[cc];
            #pragma unroll
            for (int r = 0; r < 4; r++)
                C[(size_t)(rbase + r) * N_OUT + cc] =
                    sx[rbase + r] * mast[mi][ni][r] + bb;
        }
    }
#undef STAGE
}

extern "C" void kernel_launch(void* const* d_in, const int* in_sizes, int n_in,
                              void* d_out, int out_size, void* d_ws, size_t ws_size,
                              hipStream_t stream) {
    const float* x    = (const float*)d_in[0];
    const float* w    = (const float*)d_in[1];
    const float* bias = (const float*)d_in[2];
    float* out = (float*)d_out;

    unsigned char* xq = (unsigned char*)d_ws;                       // 4 MB
    unsigned char* wq = xq + (size_t)M_TOK * KB;                    // 8 MB
    float* swt = (float*)(wq + (size_t)N_OUT * KB);                 // 512 KB, [32][4096]
    float* sx  = swt + (size_t)(K_IN / 128) * N_OUT;                // 8 KB

    quant_fused_kernel<<<XBLK + WBLK, 256, 0, stream>>>(x, w, xq, sx, wq, swt);
    gemm_mx4_kernel<<<dim3(N_OUT / 128, M_TOK / 128), 256, 0, stream>>>(
        xq, sx, wq, swt, bias, out);
}

// Round 3
// 159.259 us; speedup vs baseline: 1.0497x; 1.0497x over previous
//
#include <hip/hip_runtime.h>

// y = q_tok(x) @ q_grp(W)^T + bias, factored exactly:
//   q(x) = g_x * s_x[m], q(W) = g_w * s_w[n,grp] (grp=128 along K)
//   y[m,n] = s_x[m] * sum_grp s_w[n,grp] * (sum_{k in grp} g_x g_w)
// R8: revert gemm to the verified R6 double-buffer/2-barrier structure
// (R7's runtime buffer rotation + sched_barrier walls defeated address
// hoisting and regressed). Change: tile 128x64 -> grid 1024 blocks =
// 4 blocks/CU (was 512 = 2/CU, grid-capped occupancy). LDS 32 KB/block.
// Quant unchanged from R7 (coalesced float4 x-role).

#define M_TOK 2048
#define N_OUT 4096
#define K_IN  4096
#define KB    2048    // packed fp4 bytes per K row (K_IN/2)
#define XBLK  2048    // x-role: one block per token row
#define WBLK  8192    // w-role: 2048 floats (16 groups) per block

typedef __attribute__((ext_vector_type(4))) int   int4v;
typedef __attribute__((ext_vector_type(8))) int   int8v;
typedef __attribute__((ext_vector_type(4))) float floatx4;

// fp4-e2m1 nibble via scale-premultiplied decision thresholds
// T = {.25,.75,1.25,1.75,2.5,3.5,5}*scale; codes 0..7 = {0,.5,1,1.5,2,3,4,6}
__device__ __forceinline__ unsigned int q_nib(
    float v, float t0, float t1, float t2, float t3, float t4, float t5, float t6)
{
    float a = fabsf(v);
    unsigned int m =
        a < t0 ? 0u : a < t1 ? 1u : a < t2 ? 2u : a < t3 ? 3u :
        a < t4 ? 4u : a < t5 ? 5u : a < t6 ? 6u : 7u;
    return m | ((__float_as_uint(v) >> 28) & 0x8u);
}

#define MK_THR(scale) \
    const float t0 = 0.25f * (scale), t1 = 0.75f * (scale), \
                t2 = 1.25f * (scale), t3 = 1.75f * (scale), \
                t4 = 2.5f  * (scale), t5 = 3.5f  * (scale), \
                t6 = 5.0f  * (scale);

// ---------- fused quant: blocks [0,XBLK) per-token x, rest per-group w ----------
__global__ __launch_bounds__(256) void quant_fused_kernel(
    const float* __restrict__ x, const float* __restrict__ w,
    unsigned char* __restrict__ xq, float* __restrict__ sx,
    unsigned char* __restrict__ wq, float* __restrict__ swt)
{
    const int t = threadIdx.x;
    const int lane = t & 63, wid = t >> 6;

    if (blockIdx.x < XBLK) {
        // ---- per-token row of 4096: clamp [-3,3], scale = absmax/6 ----
        // coalesced: phase i loads float4 at i*1024 + t*4 (16B/lane contiguous)
        const int row = blockIdx.x;
        const float* xr = x + (size_t)row * K_IN;
        float4 v[4];
        float amax = 0.0f;
        #pragma unroll
        for (int i = 0; i < 4; i++) {
            float4 a = *(const float4*)(xr + i * 1024 + t * 4);
            a.x = fminf(fmaxf(a.x, -3.0f), 3.0f);
            a.y = fminf(fmaxf(a.y, -3.0f), 3.0f);
            a.z = fminf(fmaxf(a.z, -3.0f), 3.0f);
            a.w = fminf(fmaxf(a.w, -3.0f), 3.0f);
            v[i] = a;
            amax = fmaxf(amax, fmaxf(fmaxf(fabsf(a.x), fabsf(a.y)),
                                     fmaxf(fabsf(a.z), fabsf(a.w))));
        }
        #pragma unroll
        for (int off = 32; off; off >>= 1)
            amax = fmaxf(amax, __shfl_xor(amax, off));
        __shared__ float smax[4];
        if (lane == 0) smax[wid] = amax;
        __syncthreads();
        amax = fmaxf(fmaxf(smax[0], smax[1]), fmaxf(smax[2], smax[3]));

        const float scale = amax / 6.0f;
        if (t == 0) sx[row] = scale;
        MK_THR(scale);
        unsigned char* xo = xq + (size_t)row * KB;
        #pragma unroll
        for (int i = 0; i < 4; i++) {
            unsigned int u = q_nib(v[i].x, t0,t1,t2,t3,t4,t5,t6)
                           | (q_nib(v[i].y, t0,t1,t2,t3,t4,t5,t6) << 4)
                           | (q_nib(v[i].z, t0,t1,t2,t3,t4,t5,t6) << 8)
                           | (q_nib(v[i].w, t0,t1,t2,t3,t4,t5,t6) << 12);
            *(unsigned short*)(xo + i * 512 + t * 2) = (unsigned short)u;
        }
    } else {
        // ---- per-group w: block = 2048 floats = 16 groups; 16 lanes/group,
        //      8 consecutive elements per lane -> one packed uint ----
        const int b = blockIdx.x - XBLK;
        const float* base = w + (size_t)b * 2048 + t * 8;
        float4 v0 = *(const float4*)base;
        float4 v1 = *(const float4*)(base + 4);
        float vals[8] = {v0.x, v0.y, v0.z, v0.w, v1.x, v1.y, v1.z, v1.w};
        float amax = 0.0f;
        #pragma unroll
        for (int j = 0; j < 8; j++) amax = fmaxf(amax, fabsf(vals[j]));
        #pragma unroll
        for (int off = 8; off; off >>= 1)   // reduce within 16-lane cluster
            amax = fmaxf(amax, __shfl_xor(amax, off));
        const float scale = amax / 6.0f;
        const int G = b * 16 + (t >> 4);    // flat group id = n*32 + gk
        if ((lane & 15) == 0) swt[(size_t)(G & 31) * N_OUT + (G >> 5)] = scale;
        MK_THR(scale);
        unsigned int u = 0;
        #pragma unroll
        for (int j = 0; j < 8; j++)
            u |= q_nib(vals[j], t0,t1,t2,t3,t4,t5,t6) << (4 * j);
        *(unsigned int*)(wq + (size_t)b * 1024 + t * 4) = u;
    }
}

// ---------- async 16B global->LDS ----------
__device__ __forceinline__ void gld16(const unsigned char* g, unsigned char* l) {
    __builtin_amdgcn_global_load_lds(
        (const __attribute__((address_space(1))) void*)g,
        (__attribute__((address_space(3))) void*)l, 16, 0, 0);
}

// ---------- MX-fp4 GEMM, BK=128 = one quant group per MFMA ----------
// Tile 128x64, 4 waves (2m x 2n), wave tile 64x32, double-buffered LDS,
// counted vmcnt, static g&1 buffer index, setprio around MFMA cluster.
__global__ __launch_bounds__(256, 4) void gemm_mx4_kernel(
    const unsigned char* __restrict__ A, const float* __restrict__ sx,
    const unsigned char* __restrict__ B, const float* __restrict__ swt,
    const float* __restrict__ bias, float* __restrict__ C)
{
    __shared__ __align__(16) unsigned char As[2][128 * 64];  // 2 x 8 KB
    __shared__ __align__(16) unsigned char Bs[2][64 * 64];   // 2 x 4 KB
    __shared__ __align__(16) float svs[32][64];              // 8 KB scales

    const int tid = threadIdx.x;
    const int m0 = blockIdx.y * 128;
    const int n0 = blockIdx.x * 64;
    const int lane = tid & 63;
    const int wid  = tid >> 6;
    const int wm = (wid & 1) * 64;   // wave m-offset: 0/64
    const int wn = (wid >> 1) * 32;  // wave n-offset: 0/32
    const int lr = lane & 15;
    const int lq = lane >> 4;

    floatx4 mast[4][2] = {};

    // staging: rotation swizzle phys=(c+row)&3, inverse applied on the
    // global source so the LDS dest stays wave-uniform + lane*16.
    // A: 512 chunks (2/thread), B: 256 chunks (1/thread)
    const unsigned char* gA[2];
    const unsigned char* gB;
    int ldstA[2], ldstB;
    #pragma unroll
    for (int i = 0; i < 2; i++) {
        const int P = tid + i * 256;
        const int row = P >> 2, ph = P & 3;
        const int c = (ph - row) & 3;
        gA[i] = A + (size_t)(m0 + row) * KB + c * 16;
        ldstA[i] = P * 16;
    }
    {
        const int row = tid >> 2, ph = tid & 3;
        const int c = (ph - row) & 3;
        gB = B + (size_t)(n0 + row) * KB + c * 16;
        ldstB = tid * 16;
    }

#define STAGE(gg, ss) do {                                     \
        const int koff_ = (gg) * 64;                           \
        gld16(gA[0] + koff_, &As[ss][ldstA[0]]);               \
        gld16(gA[1] + koff_, &As[ss][ldstA[1]]);               \
        gld16(gB    + koff_, &Bs[ss][ldstB]);                  \
    } while (0)

    // one-time stage of this block's weight scales: swt[g][n0..n0+64)
    // (before STAGE(0) so the compiler's load-use waits don't drain gld16s)
    {
        float4 tmp[2];
        #pragma unroll
        for (int i = 0; i < 2; i++) {
            const int flat = tid + i * 256;      // float4 index, 512 total
            const int g = flat >> 4, c = (flat & 15) << 2;
            tmp[i] = *(const float4*)(swt + (size_t)g * N_OUT + n0 + c);
        }
        #pragma unroll
        for (int i = 0; i < 2; i++) {
            const int flat = tid + i * 256;
            const int g = flat >> 4, c = (flat & 15) << 2;
            *(float4*)&svs[g][c] = tmp[i];
        }
    }
    // prologue: stage k-group 0 into buffer 0
    STAGE(0, 0);
    asm volatile("s_waitcnt lgkmcnt(0)" ::: "memory");  // svs ds_writes done

    const floatx4 zero = {0.0f, 0.0f, 0.0f, 0.0f};

    #pragma unroll 2
    for (int g = 0; g < 32; g++) {
        const int cur = g & 1;
        if (g < 31) {
            // issue next tile's 3 loads; keep in flight -- wait only for
            // the 3 older loads (current buffer)
            STAGE(g + 1, cur ^ 1);
            asm volatile("s_waitcnt vmcnt(3)" ::: "memory");
        } else {
            asm volatile("s_waitcnt vmcnt(0)" ::: "memory");
        }
        __builtin_amdgcn_s_barrier();            // buf[cur] ready for all
        __builtin_amdgcn_sched_barrier(0);

        float sv[2];
        #pragma unroll
        for (int ni = 0; ni < 2; ni++)
            sv[ni] = svs[g][wn + ni * 16 + lr];

        // fragment reads: fp4 => one 16B chunk per fragment (32 elems/lane)
        int8v af[4], bf[2];
        #pragma unroll
        for (int mi = 0; mi < 4; mi++) {
            const int row = wm + mi * 16 + lr;
            const int slot = (lq + row) & 3;
            int4v d = *(const int4v*)&As[cur][row * 64 + slot * 16];
            af[mi] = (int8v){d[0], d[1], d[2], d[3], 0, 0, 0, 0};
        }
        #pragma unroll
        for (int ni = 0; ni < 2; ni++) {
            const int row = wn + ni * 16 + lr;
            const int slot = (lq + row) & 3;
            int4v d = *(const int4v*)&Bs[cur][row * 64 + slot * 16];
            bf[ni] = (int8v){d[0], d[1], d[2], d[3], 0, 0, 0, 0};
        }
        asm volatile("s_waitcnt lgkmcnt(0)" ::: "memory");
        __builtin_amdgcn_sched_barrier(0);       // rule #18: pin MFMA below
        __builtin_amdgcn_s_barrier();            // buf[cur] free for overwrite

        __builtin_amdgcn_s_setprio(1);
        #pragma unroll
        for (int mi = 0; mi < 4; mi++)
            #pragma unroll
            for (int ni = 0; ni < 2; ni++) {
                floatx4 tacc = __builtin_amdgcn_mfma_scale_f32_16x16x128_f8f6f4(
                    af[mi], bf[ni], zero, 4, 4,          // cbsz=blgp=4 -> fp4
                    0, 0x7F7F7F7F, 0, 0x7F7F7F7F);       // e8m0 scales = 1.0
                mast[mi][ni] += sv[ni] * tacc;
            }
        __builtin_amdgcn_s_setprio(0);
    }

    // epilogue: C/D layout col=lane&15, row=(lane>>4)*4+reg [m89/m91]
    #pragma unroll
    for (int mi = 0; mi < 4; mi++) {
        const int rbase = m0 + wm + mi * 16 + lq * 4;
        #pragma unroll
        for (int ni = 0; ni < 2; ni++) {
            const int cc = n0 + wn + ni * 16 + lr;
            const float bb = bias[cc];
            #pragma unroll
            for (int r = 0; r < 4; r++)
                C[(size_t)(rbase + r) * N_OUT + cc] =
                    sx[rbase + r] * mast[mi][ni][r] + bb;
        }
    }
#undef STAGE
}

extern "C" void kernel_launch(void* const* d_in, const int* in_sizes, int n_in,
                              void* d_out, int out_size, void* d_ws, size_t ws_size,
                              hipStream_t stream) {
    const float* x    = (const float*)d_in[0];
    const float* w    = (const float*)d_in[1];
    const float* bias = (const float*)d_in[2];
    float* out = (float*)d_out;

    unsigned char* xq = (unsigned char*)d_ws;                       // 4 MB
    unsigned char* wq = xq + (size_t)M_TOK * KB;                    // 8 MB
    float* swt = (float*)(wq + (size_t)N_OUT * KB);                 // 512 KB, [32][4096]
    float* sx  = swt + (size_t)(K_IN / 128) * N_OUT;                // 8 KB

    quant_fused_kernel<<<XBLK + WBLK, 256, 0, stream>>>(x, w, xq, sx, wq, swt);
    gemm_mx4_kernel<<<dim3(N_OUT / 64, M_TOK / 128), 256, 0, stream>>>(
        xq, sx, wq, swt, bias, out);
}